// Round 7
// baseline (11543.311 us; speedup 1.0000x reference)
//
#include <hip/hip_runtime.h>
#include <math.h>

// Problem constants: B=8, S=16, CIN=128, H=W=64, D=64
// Padded field layout for conv inputs: [b][c][66 rows][72 cols], value(x,y) at [y+1][x+4],
// borders zero. PF = 8*64*66*72 = 2,433,024 floats.

__device__ __forceinline__ float sigf(float x){ return 1.0f/(1.0f + expf(-x)); }

#define FMA4(A, W, V0, V1, V2, V3) { (A).x += (W)*(V0); (A).y += (W)*(V1); (A).z += (W)*(V2); (A).w += (W)*(V3); }

// ---------------------------------------------------------------------------
// reshape clstm_w (256,128,3,3) -> w3[rk][ocg*8 + g*2 + e], rk = ic*9+k,
// where oc_global = g*64 + ocg*2 + e  (g = gate 0..3, ocg 0..31, e 0..1).
// Thread ocg then owns all 4 gates of channels {2*ocg, 2*ocg+1}.
__global__ __launch_bounds__(256) void k_w3(const float* __restrict__ cw, float* __restrict__ w3){
    int idx = blockIdx.x*256 + threadIdx.x;
    if (idx < 294912){
        int col = idx & 255;            // ocg*8 + g*2 + e
        int rk  = idx >> 8;             // ic*9 + k
        int ocg = col >> 3, j = col & 7;
        int g = j >> 1, e = j & 1;
        int oc = g*64 + ocg*2 + e;
        w3[idx] = cw[oc*1152 + rk];
    }
}

// ---------------------------------------------------------------------------
// 1x1 proj conv + BN partial sums. Writes raw t==0 slice into x0 buffer.
__global__ __launch_bounds__(256) void k_proj(const float* __restrict__ x, const float* __restrict__ pw,
                                              float* __restrict__ x0raw, float* __restrict__ psum,
                                              float* __restrict__ psumsq){
    __shared__ __align__(16) float smem[8192];
    const int tile = blockIdx.x;
    const int n    = blockIdx.y;
    const int tid  = threadIdx.x;
    const int pj = tid & 63, dg = tid >> 6;

    for (int r = tid; r < 8192; r += 256){
        int c = r >> 6, d = r & 63;
        smem[r] = pw[d*128 + c];
    }
    __syncthreads();

    const int p0 = tile*256 + pj*4;
    float4 acc[16];
#pragma unroll
    for (int i=0;i<16;i++) acc[i] = make_float4(0.f,0.f,0.f,0.f);

    const float* xb = x + (((size_t)n) << 19) + p0;
    for (int c = 0; c < 128; ++c){
        float4 xv = *(const float4*)(xb + ((size_t)c << 12));
        const float4* wr = (const float4*)(smem + c*64 + dg*16);
#pragma unroll
        for (int q=0;q<4;++q){
            float4 w4 = wr[q];
            FMA4(acc[q*4+0], w4.x, xv.x, xv.y, xv.z, xv.w);
            FMA4(acc[q*4+1], w4.y, xv.x, xv.y, xv.z, xv.w);
            FMA4(acc[q*4+2], w4.z, xv.x, xv.y, xv.z, xv.w);
            FMA4(acc[q*4+3], w4.w, xv.x, xv.y, xv.z, xv.w);
        }
    }

    const int t = n & 15, b = n >> 4;
    if (t == 0){
#pragma unroll
        for (int i=0;i<16;i++){
            int dd = dg*16 + i;
            *(float4*)(x0raw + (((size_t)(b*64 + dd)) << 12) + p0) = acc[i];
        }
    }
    float ls[16], lss[16];
#pragma unroll
    for (int i=0;i<16;i++){
        float4 a = acc[i];
        ls[i]  = a.x + a.y + a.z + a.w;
        lss[i] = a.x*a.x + a.y*a.y + a.z*a.z + a.w*a.w;
    }
    __syncthreads();
#pragma unroll
    for (int i=0;i<16;i++) smem[pj*65 + dg*16 + i] = ls[i];
    __syncthreads();
    if (tid < 64){
        float s = 0.f;
        for (int p=0;p<64;p++) s += smem[p*65 + tid];
        psum[((n*16 + tile) << 6) + tid] = s;
    }
    __syncthreads();
#pragma unroll
    for (int i=0;i<16;i++) smem[pj*65 + dg*16 + i] = lss[i];
    __syncthreads();
    if (tid < 64){
        float s = 0.f;
        for (int p=0;p<64;p++) s += smem[p*65 + tid];
        psumsq[((n*16 + tile) << 6) + tid] = s;
    }
}

// ---------------------------------------------------------------------------
__global__ __launch_bounds__(64) void k_bnfinal(const float* __restrict__ psum, const float* __restrict__ psumsq,
                                                const float* __restrict__ gamma, const float* __restrict__ beta,
                                                float* __restrict__ scale, float* __restrict__ shift,
                                                float* __restrict__ xmean){
    const int d = threadIdx.x;
    double gs = 0.0, gss = 0.0;
    for (int n=0;n<128;n++){
        float s = 0.f, ss = 0.f;
        for (int tl=0;tl<16;tl++){
            s  += psum  [((n*16+tl)<<6) + d];
            ss += psumsq[((n*16+tl)<<6) + d];
        }
        gs += (double)s; gss += (double)ss;
    }
    double mu  = gs  / 524288.0;
    double var = gss / 524288.0 - mu*mu;
    double sc  = (double)gamma[d] / sqrt(var + 1e-5);
    float scf = (float)sc;
    float shf = (float)((double)beta[d] - mu*sc);
    scale[d] = scf; shift[d] = shf;
    for (int n=0;n<128;n++){
        float s = 0.f;
        for (int tl=0;tl<16;tl++) s += psum[((n*16+tl)<<6) + d];
        xmean[(n<<6) + d] = (s * (1.f/4096.f)) * scf + shf;
    }
}

// ---------------------------------------------------------------------------
// Zero a float4-multiple region (yhat_p | hfA_p | hfB_p | cf, contiguous).
__global__ __launch_bounds__(256) void k_zero(float* __restrict__ z){
    size_t i = ((size_t)blockIdx.x*256 + threadIdx.x)*4;
    *(float4*)(z + i) = make_float4(0.f,0.f,0.f,0.f);
}

// ---------------------------------------------------------------------------
// Apply BN to x0 (in place), write yhat_p interior, init states, P=P_init.
__global__ __launch_bounds__(256) void k_init(const float* __restrict__ scale, const float* __restrict__ shift,
                                              float* __restrict__ x0, float* __restrict__ yhat_p,
                                              const float* __restrict__ Pinit, float* __restrict__ Pg,
                                              float* __restrict__ hQ, float* __restrict__ cQ,
                                              float* __restrict__ hR, float* __restrict__ cR){
    size_t idx = (size_t)blockIdx.x*256 + threadIdx.x;   // 2,097,152 total
    int d = (int)((idx >> 12) & 63);
    float v = x0[idx]*scale[d] + shift[d];
    x0[idx] = v;
    int b = (int)(idx >> 18), r = (int)((idx >> 6) & 63), xx = (int)(idx & 63);
    yhat_p[(((size_t)(b*64 + d))*66 + r + 1)*72 + xx + 4] = v;
    if (idx < 512){ hQ[idx]=0.f; cQ[idx]=0.f; hR[idx]=0.f; cR[idx]=0.f; }
    if (idx < 32768) Pg[idx] = Pinit[idx & 4095];
}

// ---------------------------------------------------------------------------
// ConvLSTM step, fused with y_tick. grid (64 rows, 8 b) = 512 blocks (2/CU).
// Thread: pxg = tid&7 (8 px), ocg = tid>>3 (8 oc = 4 gates x 2 channels).
// acc = 64 floats. 64 chunks of 2 ic, double-buffered LDS (1 barrier/chunk),
// register-staged (issue-early/commit-late). Gating fully in registers.
// Tail: h row tile in LDS -> y_tick = fcf(h) + row partial sums (k_ytick fused).
// LDS map: buf0 [0..5040) | buf1 [5040..10080); after loop:
//   fw_s [0..4352) stride 68, h_s [4352..8704) stride 68, red [8704..9280).
__global__ __launch_bounds__(256,2) void k_conv(const float* __restrict__ yhat_p, const float* __restrict__ hfin_p,
                                                float* __restrict__ hfout_p, float* __restrict__ cf,
                                                const float* __restrict__ w3, const float* __restrict__ cb,
                                                const float* __restrict__ fcf_w, const float* __restrict__ fcf_b,
                                                float* __restrict__ ytick,
                                                float* __restrict__ hfpart, float* __restrict__ ytpartR){
    __shared__ __align__(16) float smem[10080];
    const int BUF = 5040, HS = 4352, REDZ = 8704;
    const int row = blockIdx.x;
    const int b   = blockIdx.y;
    const int tid = threadIdx.x;
    const int pxg = tid & 7;
    const int ocg = tid >> 3;
    const int px0 = pxg*8;

    float4 acc4[16];                  // [j*2 + h], j = g*2+e2, h = px 0-3 / 4-7
#pragma unroll
    for (int i=0;i<16;i++) acc4[i] = make_float4(0.f,0.f,0.f,0.f);

    // chunk staging: 1152 w-float4 (2ic x 9k x 256) + 108 in-float4 (2ic x 3r x 18)
    float4 st[5];
    auto issue = [&](int icc){
#pragma unroll
        for (int j=0;j<5;++j){
            int s = tid + j*256;
            if (s < 1152){
                st[j] = ((const float4*)w3)[(size_t)icc*1152 + s];
            } else if (s < 1260){
                int si = s - 1152;
                int icl = si/54, rem = si - icl*54, r = rem/18, x4 = rem - r*18;
                int ic  = icc*2 + icl;
                const float* f = (ic < 64) ? yhat_p : hfin_p;
                st[j] = *(const float4*)(f + (((size_t)(b*64 + (ic & 63)))*66 + row + r)*72 + x4*4);
            }
        }
    };
    auto commit = [&](int buf){
#pragma unroll
        for (int j=0;j<5;++j){
            int s = tid + j*256;
            if (s < 1260) *(float4*)(smem + buf*BUF + s*4) = st[j];
        }
    };

    issue(0); commit(0); __syncthreads();
    int p = 0;
    for (int icc = 0; icc < 64; ++icc){
        if (icc < 63){
            issue(icc+1);                      // loads in flight under compute
        } else {
#pragma unroll
            for (int j=0;j<4;++j) st[j] = ((const float4*)fcf_w)[tid + j*256];
        }
        const float* wb = smem + p*BUF;
        const float* ib = wb + 4608;
#pragma unroll
        for (int icl=0; icl<2; ++icl){
            float v[3][10];
#pragma unroll
            for (int ky=0;ky<3;++ky){
                const float* vp = ib + icl*216 + ky*72 + px0;
                v[ky][0] = vp[3];
                float4 va = *(const float4*)(vp+4);
                float4 vb = *(const float4*)(vp+8);
                v[ky][1]=va.x; v[ky][2]=va.y; v[ky][3]=va.z; v[ky][4]=va.w;
                v[ky][5]=vb.x; v[ky][6]=vb.y; v[ky][7]=vb.z; v[ky][8]=vb.w;
                v[ky][9] = vp[12];
            }
#pragma unroll
            for (int k=0;k<9;++k){
                const int ky = k/3, kx = k - ky*3;
                const float* wr = wb + (icl*9+k)*256 + ocg*8;
                float4 wa  = *(const float4*)(wr);
                float4 wb4 = *(const float4*)(wr+4);
                const float u0=v[ky][kx+0], u1=v[ky][kx+1], u2=v[ky][kx+2], u3=v[ky][kx+3];
                const float u4=v[ky][kx+4], u5=v[ky][kx+5], u6=v[ky][kx+6], u7=v[ky][kx+7];
                FMA4(acc4[0],  wa.x,  u0,u1,u2,u3);  FMA4(acc4[1],  wa.x,  u4,u5,u6,u7);
                FMA4(acc4[2],  wa.y,  u0,u1,u2,u3);  FMA4(acc4[3],  wa.y,  u4,u5,u6,u7);
                FMA4(acc4[4],  wa.z,  u0,u1,u2,u3);  FMA4(acc4[5],  wa.z,  u4,u5,u6,u7);
                FMA4(acc4[6],  wa.w,  u0,u1,u2,u3);  FMA4(acc4[7],  wa.w,  u4,u5,u6,u7);
                FMA4(acc4[8],  wb4.x, u0,u1,u2,u3);  FMA4(acc4[9],  wb4.x, u4,u5,u6,u7);
                FMA4(acc4[10], wb4.y, u0,u1,u2,u3);  FMA4(acc4[11], wb4.y, u4,u5,u6,u7);
                FMA4(acc4[12], wb4.z, u0,u1,u2,u3);  FMA4(acc4[13], wb4.z, u4,u5,u6,u7);
                FMA4(acc4[14], wb4.w, u0,u1,u2,u3);  FMA4(acc4[15], wb4.w, u4,u5,u6,u7);
            }
        }
        if (icc < 63){
            commit(p^1);                        // other buffer: fully consumed last iter
        } else {
            // commit fcf_w into fw_s (stride 68, bank-spread), region = free buf0
#pragma unroll
            for (int j=0;j<4;++j){
                int s = tid + j*256;
                int dp = s >> 4, c4 = s & 15;
                *(float4*)(smem + dp*68 + c4*4) = st[j];
            }
        }
        __syncthreads();
        p ^= 1;
    }

    // ---- gating fully in registers: j = g*2+e2, gate order i,f,o,g ----
#pragma unroll
    for (int e2=0;e2<2;++e2){
        const int d = ocg*2 + e2;
        const float biv = cb[d], bfv = cb[64+d], bov = cb[128+d], bgv = cb[192+d];
        const size_t gidx = (((size_t)(b*64 + d)) << 12) + row*64 + px0;
        const size_t pidx = (((size_t)(b*64 + d))*66 + row + 1)*72 + px0 + 4;
#pragma unroll
        for (int h2=0;h2<2;++h2){
            float4 zi = acc4[(0+e2)*2 + h2];
            float4 zf = acc4[(2+e2)*2 + h2];
            float4 zo = acc4[(4+e2)*2 + h2];
            float4 zg = acc4[(6+e2)*2 + h2];
            float4 c_old = *(const float4*)(cf + gidx + h2*4);
            float4 c2, hh;
            c2.x = sigf(zf.x+bfv)*c_old.x + sigf(zi.x+biv)*tanhf(zg.x+bgv); hh.x = sigf(zo.x+bov)*tanhf(c2.x);
            c2.y = sigf(zf.y+bfv)*c_old.y + sigf(zi.y+biv)*tanhf(zg.y+bgv); hh.y = sigf(zo.y+bov)*tanhf(c2.y);
            c2.z = sigf(zf.z+bfv)*c_old.z + sigf(zi.z+biv)*tanhf(zg.z+bgv); hh.z = sigf(zo.z+bov)*tanhf(c2.z);
            c2.w = sigf(zf.w+bfv)*c_old.w + sigf(zi.w+biv)*tanhf(zg.w+bgv); hh.w = sigf(zo.w+bov)*tanhf(c2.w);
            *(float4*)(cf + gidx + h2*4) = c2;
            *(float4*)(hfout_p + pidx + h2*4) = hh;
            *(float4*)(smem + HS + d*68 + px0 + h2*4) = hh;
        }
    }
    __syncthreads();

    // ---- fused y_tick: yt[d'][px] = fcf_b[d'] + sum_d fcf_w[d'][d] * h[d][px] ----
    const int d0 = ocg*2;
    float4 yt[4];
    {
        float b0 = fcf_b[d0], b1 = fcf_b[d0+1];
        yt[0] = make_float4(b0,b0,b0,b0); yt[1] = yt[0];
        yt[2] = make_float4(b1,b1,b1,b1); yt[3] = yt[2];
    }
    for (int d=0; d<64; ++d){
        float4 h0 = *(const float4*)(smem + HS + d*68 + px0);
        float4 h1 = *(const float4*)(smem + HS + d*68 + px0 + 4);
        float w0 = smem[(d0  )*68 + d];
        float w1 = smem[(d0+1)*68 + d];
        FMA4(yt[0], w0, h0.x,h0.y,h0.z,h0.w);
        FMA4(yt[1], w0, h1.x,h1.y,h1.z,h1.w);
        FMA4(yt[2], w1, h0.x,h0.y,h0.z,h0.w);
        FMA4(yt[3], w1, h1.x,h1.y,h1.z,h1.w);
    }
#pragma unroll
    for (int e2=0;e2<2;++e2){
        const int dp = d0 + e2;
        size_t yi = (((size_t)(b*64 + dp)) << 12) + row*64 + px0;
        *(float4*)(ytick + yi)     = yt[e2*2+0];
        *(float4*)(ytick + yi + 4) = yt[e2*2+1];
        float4 a = yt[e2*2], c = yt[e2*2+1];
        smem[REDZ + dp*9 + pxg] = a.x+a.y+a.z+a.w + c.x+c.y+c.z+c.w;
    }
    __syncthreads();
    if (tid < 64){
        float s = 0.f;
#pragma unroll 8
        for (int px=0;px<64;++px) s += smem[HS + tid*68 + px];
        hfpart[((b*64 + row) << 6) + tid] = s;
        float s2 = 0.f;
#pragma unroll
        for (int q=0;q<8;++q) s2 += smem[REDZ + tid*9 + q];
        ytpartR[((b*64 + row) << 6) + tid] = s2;
    }
}

// ---------------------------------------------------------------------------
// Per-step small ops + Kalman update. grid 8 (b), block 256.
__global__ __launch_bounds__(256) void k_small(int t,
        const float* __restrict__ hfpart, const float* __restrict__ ytpartR, const float* __restrict__ xmean,
        const float* __restrict__ fcF_w, const float* __restrict__ fcF_b,
        const float* __restrict__ lq_wih, const float* __restrict__ lq_whh,
        const float* __restrict__ lq_bih, const float* __restrict__ lq_bhh,
        const float* __restrict__ lr_wih, const float* __restrict__ lr_whh,
        const float* __restrict__ lr_bih, const float* __restrict__ lr_bhh,
        const float* __restrict__ fcQ_w, const float* __restrict__ fcQ_b,
        const float* __restrict__ fcR_w, const float* __restrict__ fcR_b,
        float* __restrict__ hQ, float* __restrict__ cQ, float* __restrict__ hR, float* __restrict__ cR,
        float* __restrict__ Pg, float* __restrict__ Kg){
    const int b = blockIdx.x, tid = threadIdx.x;
    __shared__ __align__(16) float aug[64*132];
    __shared__ __align__(16) float Pl[4096];
    __shared__ float hfm[64], ytm[64], xm[64], Fv[64], Qd[64], Rd[64], rds[64];
    __shared__ float hq_s[64], cq_s[64], hr_s[64], cr_s[64];
    __shared__ float gq[256], gr[256];

    if (tid < 64){
        float s = 0.f;
        for (int r=0;r<64;r++) s += hfpart[((b*64 + r) << 6) + tid];
        hfm[tid] = s * (1.f/4096.f);
        float s2 = 0.f;
        for (int r=0;r<64;r++) s2 += ytpartR[((b*64 + r) << 6) + tid];
        ytm[tid] = s2 * (1.f/4096.f);
        xm[tid] = xmean[((b*16 + t) << 6) + tid];
        hq_s[tid] = hQ[b*64+tid]; cq_s[tid] = cQ[b*64+tid];
        hr_s[tid] = hR[b*64+tid]; cr_s[tid] = cR[b*64+tid];
    }
    __syncthreads();
    {
        int j = tid;
        float aq = lq_bih[j] + lq_bhh[j];
        float ar = lr_bih[j] + lr_bhh[j];
        for (int e=0;e<64;e++){
            aq += lq_wih[j*64+e]*ytm[e] + lq_whh[j*64+e]*hq_s[e];
            ar += lr_wih[j*64+e]*xm[e]  + lr_whh[j*64+e]*hr_s[e];
        }
        gq[j] = aq; gr[j] = ar;
    }
    if (tid < 64){
        float a = fcF_b[tid];
        for (int e=0;e<64;e++) a += fcF_w[tid*64+e]*hfm[e];
        Fv[tid] = a;
    }
    __syncthreads();
    if (tid < 64){   // lstm_cell gate order: i, f, g, o
        int dd = tid;
        float gi = gq[dd], gf = gq[64+dd], gg = gq[128+dd], go = gq[192+dd];
        float c2 = sigf(gf)*cq_s[dd] + sigf(gi)*tanhf(gg);
        float h2 = sigf(go)*tanhf(c2);
        cq_s[dd] = c2; hq_s[dd] = h2;
        gi = gr[dd]; gf = gr[64+dd]; gg = gr[128+dd]; go = gr[192+dd];
        c2 = sigf(gf)*cr_s[dd] + sigf(gi)*tanhf(gg);
        h2 = sigf(go)*tanhf(c2);
        cr_s[dd] = c2; hr_s[dd] = h2;
    }
    __syncthreads();
    if (tid < 64){
        float aq_ = fcQ_b[tid], ar_ = fcR_b[tid];
        for (int e=0;e<64;e++){ aq_ += fcQ_w[tid*64+e]*hq_s[e]; ar_ += fcR_w[tid*64+e]*hr_s[e]; }
        Qd[tid] = expf(aq_); Rd[tid] = expf(ar_);
        hQ[b*64+tid] = hq_s[tid]; cQ[b*64+tid] = cq_s[tid];
        hR[b*64+tid] = hr_s[tid]; cR[b*64+tid] = cr_s[tid];
    }
    __syncthreads();
    // P = P*FF + diag(Qd); aug = [A=P+diag(Rd) | P]
    for (int r = tid; r < 4096; r += 256){
        int i = r >> 6, j = r & 63;
        float p = Pg[((size_t)b << 12) + r] * Fv[i]*Fv[j] + (i==j ? Qd[i] : 0.f);
        Pl[r] = p;
        aug[i*132 + 64 + j] = p;
        aug[i*132 + j]      = p + (i==j ? Rd[i] : 0.f);
    }
    __syncthreads();
    const int r_ = tid & 63, cq_ = tid >> 6;
    for (int k = 0; k < 64; ++k){
        float akk = aug[k*132 + k];
        float f = aug[r_*132 + k] / akk;
        if (r_ != k){
#pragma unroll
            for (int u = 0; u < 8; ++u){
                int c4 = cq_*32 + u*4;
                if (c4 + 3 > k){
                    float4 pv = *(const float4*)(aug + k*132 + c4);
                    float4 av = *(const float4*)(aug + r_*132 + c4);
                    av.x = (c4+0 > k) ? av.x - f*pv.x : av.x;
                    av.y = (c4+1 > k) ? av.y - f*pv.y : av.y;
                    av.z = (c4+2 > k) ? av.z - f*pv.z : av.z;
                    av.w = (c4+3 > k) ? av.w - f*pv.w : av.w;
                    *(float4*)(aug + r_*132 + c4) = av;
                }
            }
        }
        __syncthreads();
    }
    if (tid < 64) rds[tid] = 1.0f / aug[tid*132 + tid];
    __syncthreads();
    {
        const int i = tid >> 2, jq = tid & 3;
        float4 tv[4];
#pragma unroll
        for (int q=0;q<4;++q) tv[q] = *(const float4*)(Pl + i*64 + jq*16 + q*4);
        for (int m=0;m<64;++m){
            float kim = aug[m*132 + 64 + i] * rds[m];
#pragma unroll
            for (int q=0;q<4;++q){
                float4 pv = *(const float4*)(Pl + m*64 + jq*16 + q*4);
                tv[q].x -= kim*pv.x; tv[q].y -= kim*pv.y; tv[q].z -= kim*pv.z; tv[q].w -= kim*pv.w;
            }
        }
#pragma unroll
        for (int q=0;q<4;++q) *(float4*)(aug + i*132 + jq*16 + q*4) = tv[q];
    }
    __syncthreads();
    {
        const int i = tid >> 2, jq = tid & 3;
        float4 a2[4];
#pragma unroll
        for (int q=0;q<4;++q) a2[q] = *(const float4*)(aug + i*132 + jq*16 + q*4);
        for (int m=0;m<64;++m){
            float t1im = aug[i*132 + m];
            float kim  = aug[m*132 + 64 + i] * rds[m];
            float coef = rds[m] * (kim * Rd[m] - t1im);
#pragma unroll
            for (int q=0;q<4;++q){
                float4 yv = *(const float4*)(aug + m*132 + 64 + jq*16 + q*4);
                a2[q].x += coef*yv.x; a2[q].y += coef*yv.y; a2[q].z += coef*yv.z; a2[q].w += coef*yv.w;
            }
        }
        size_t base = ((size_t)b << 12) + (size_t)i*64;
#pragma unroll
        for (int q=0;q<4;++q) *(float4*)(Pg + base + jq*16 + q*4) = a2[q];
#pragma unroll
        for (int q=0;q<4;++q){
#pragma unroll
            for (int e=0;e<4;++e){
                int j = jq*16 + q*4 + e;
                Kg[base + j] = aug[j*132 + 64 + i] * rds[j];
            }
        }
    }
}

// ---------------------------------------------------------------------------
// y_hat = y_tick + K(x0 - y_tick); writes PADDED yhat + spatial partial sums.
// grid (32 tiles of 128 px, 8 b), block 256: pj = tid&31 (4 px), dgp = tid>>5 (8 d).
__global__ __launch_bounds__(256) void k_apply(int t, const float* __restrict__ ytick,
                                               const float* __restrict__ x0, const float* __restrict__ Kg,
                                               float* __restrict__ yhat_p, float* __restrict__ featpart){
    __shared__ __align__(16) float kt[4160];   // kt[j*65 + i] = K[i][j]  (conflict-free both ways)
    const int tile = blockIdx.x;
    const int b    = blockIdx.y;
    const int tid  = threadIdx.x;
    const int pj = tid & 31, dgp = tid >> 5;

    for (int r = tid; r < 4096; r += 256){
        int i = r >> 6, j = r & 63;
        kt[j*65 + i] = Kg[((size_t)b << 12) + r];
    }
    __syncthreads();

    const int p0 = tile*128 + pj*4;
    const int rr = p0 >> 6, xx = p0 & 63;
    float4 acc[8];
#pragma unroll
    for (int i=0;i<8;i++) acc[i] = make_float4(0.f,0.f,0.f,0.f);

    for (int j = 0; j < 64; ++j){
        size_t gi = (((size_t)(b*64 + j)) << 12) + p0;
        float4 xv = *(const float4*)(x0 + gi);
        float4 yv = *(const float4*)(ytick + gi);
        float u0 = xv.x - yv.x, u1 = xv.y - yv.y, u2 = xv.z - yv.z, u3 = xv.w - yv.w;
        const float* kr = kt + j*65 + dgp*8;
#pragma unroll
        for (int il=0; il<8; ++il){
            float kv = kr[il];
            FMA4(acc[il], kv, u0,u1,u2,u3);
        }
    }
    float ls[8];
#pragma unroll
    for (int il=0;il<8;++il){
        int d = dgp*8 + il;
        size_t gi = (((size_t)(b*64 + d)) << 12) + p0;
        float4 yv = *(const float4*)(ytick + gi);
        float4 o;
        o.x = yv.x + acc[il].x; o.y = yv.y + acc[il].y; o.z = yv.z + acc[il].z; o.w = yv.w + acc[il].w;
        *(float4*)(yhat_p + (((size_t)(b*64 + d))*66 + rr + 1)*72 + xx + 4) = o;
        ls[il] = o.x + o.y + o.z + o.w;
    }
    __syncthreads();   // kt reads done; reuse as reduction scratch
#pragma unroll
    for (int il=0;il<8;++il) kt[pj*65 + dgp*8 + il] = ls[il];
    __syncthreads();
    if (tid < 64){
        float s = 0.f;
        for (int q=0;q<32;++q) s += kt[q*65 + tid];
        featpart[(((size_t)((t*8 + b)*32 + tile)) << 6) + tid] = s;
    }
}

// ---------------------------------------------------------------------------
__global__ __launch_bounds__(64) void k_head(const float* __restrict__ featpart,
                                             const float* __restrict__ fc_w, const float* __restrict__ fc_b,
                                             const float* __restrict__ fco_w, const float* __restrict__ fco_b,
                                             const float* __restrict__ fca_w, const float* __restrict__ fca_b,
                                             float* __restrict__ out){
    const int bt = blockIdx.x;
    const int b = bt >> 4, t = bt & 15;
    __shared__ float fs[64];
    const int i = threadIdx.x;
    float s = 0.f;
    for (int tile=0;tile<32;tile++) s += featpart[(((size_t)((t*8 + b)*32 + tile)) << 6) + i];
    fs[i] = s * (1.f/4096.f);
    __syncthreads();
    float a = fc_b[i];
    for (int e=0;e<64;e++) a += fc_w[i*64+e]*fs[e];
    a = fmaxf(a, 0.f);
    float po = a * fco_w[i];
    float pa = a * fca_w[i];
    for (int off=32; off; off >>= 1){ po += __shfl_down(po, off); pa += __shfl_down(pa, off); }
    if (i == 0){
        out[bt]       = po + fco_b[0];
        out[128 + bt] = pa + fca_b[0];
    }
}

// ---------------------------------------------------------------------------
extern "C" void kernel_launch(void* const* d_in, const int* in_sizes, int n_in,
                              void* d_out, int out_size, void* d_ws, size_t ws_size,
                              hipStream_t stream){
    const float* x       = (const float*)d_in[0];
    const float* proj_w  = (const float*)d_in[1];
    const float* bn_g    = (const float*)d_in[2];
    const float* bn_b    = (const float*)d_in[3];
    const float* clstm_w = (const float*)d_in[4];
    const float* clstm_b = (const float*)d_in[5];
    const float* lq_wih  = (const float*)d_in[6];
    const float* lq_whh  = (const float*)d_in[7];
    const float* lq_bih  = (const float*)d_in[8];
    const float* lq_bhh  = (const float*)d_in[9];
    const float* lr_wih  = (const float*)d_in[10];
    const float* lr_whh  = (const float*)d_in[11];
    const float* lr_bih  = (const float*)d_in[12];
    const float* lr_bhh  = (const float*)d_in[13];
    const float* fcf_w   = (const float*)d_in[14];
    const float* fcf_b   = (const float*)d_in[15];
    const float* fcF_w   = (const float*)d_in[16];
    const float* fcF_b   = (const float*)d_in[17];
    const float* fcQ_w   = (const float*)d_in[18];
    const float* fcQ_b   = (const float*)d_in[19];
    const float* fcR_w   = (const float*)d_in[20];
    const float* fcR_b   = (const float*)d_in[21];
    const float* P_init  = (const float*)d_in[22];
    const float* fc_w    = (const float*)d_in[23];
    const float* fc_b    = (const float*)d_in[24];
    const float* fco_w   = (const float*)d_in[25];
    const float* fco_b   = (const float*)d_in[26];
    const float* fca_w   = (const float*)d_in[27];
    const float* fca_b   = (const float*)d_in[28];
    float* out = (float*)d_out;
    float* ws  = (float*)d_ws;

    const size_t PF    = 2433024;        // 8*64*66*72 padded field
    const size_t FIELD = 2097152;        // 8*64*4096
    float* yhat_p = ws;                  // PF
    float* hfA_p  = ws + PF;             // PF
    float* hfB_p  = ws + 2*PF;           // PF
    float* cf     = ws + 3*PF;           // FIELD  (zero-span = 3*PF + FIELD)
    float* x0     = cf + FIELD;          // FIELD
    float* ytick  = x0 + FIELD;          // FIELD
    float* w3     = ytick + FIELD;       // 294912
    float* psum   = w3 + 294912;         // 131072
    float* psumsq = psum + 131072;       // 131072
    float* scale  = psumsq + 131072;     // 64
    float* shift  = scale + 64;          // 64
    float* xmean  = shift + 64;          // 8192
    float* hfpart = xmean + 8192;        // 32768
    float* ytpartR= hfpart + 32768;      // 32768
    float* featpart = ytpartR + 32768;   // 262144
    float* hQ     = featpart + 262144;   // 512
    float* cQ     = hQ + 512;
    float* hR     = cQ + 512;
    float* cR     = hR + 512;
    float* Pg     = cR + 512;            // 32768
    float* Kg     = Pg + 32768;          // 32768

    hipLaunchKernelGGL(k_w3, dim3(1152), dim3(256), 0, stream, clstm_w, w3);
    hipLaunchKernelGGL(k_proj, dim3(16,128), dim3(256), 0, stream, x, proj_w, x0, psum, psumsq);
    hipLaunchKernelGGL(k_bnfinal, dim3(1), dim3(64), 0, stream, psum, psumsq, bn_g, bn_b, scale, shift, xmean);
    hipLaunchKernelGGL(k_zero, dim3(9176), dim3(256), 0, stream, ws);   // yhat_p|hfA_p|hfB_p|cf
    hipLaunchKernelGGL(k_init, dim3(8192), dim3(256), 0, stream, scale, shift, x0, yhat_p, P_init, Pg, hQ, cQ, hR, cR);

    for (int t = 0; t < 16; ++t){
        float* hf_in  = (t & 1) ? hfB_p : hfA_p;
        float* hf_out = (t & 1) ? hfA_p : hfB_p;
        hipLaunchKernelGGL(k_conv, dim3(64,8), dim3(256), 0, stream,
                           yhat_p, hf_in, hf_out, cf, w3, clstm_b,
                           fcf_w, fcf_b, ytick, hfpart, ytpartR);
        hipLaunchKernelGGL(k_small, dim3(8), dim3(256), 0, stream, t,
                           hfpart, ytpartR, xmean, fcF_w, fcF_b,
                           lq_wih, lq_whh, lq_bih, lq_bhh,
                           lr_wih, lr_whh, lr_bih, lr_bhh,
                           fcQ_w, fcQ_b, fcR_w, fcR_b,
                           hQ, cQ, hR, cR, Pg, Kg);
        hipLaunchKernelGGL(k_apply, dim3(32,8), dim3(256), 0, stream, t,
                           ytick, x0, Kg, yhat_p, featpart);
    }
    hipLaunchKernelGGL(k_head, dim3(128), dim3(64), 0, stream,
                       featpart, fc_w, fc_b, fco_w, fco_b, fca_w, fca_b, out);
}

// Round 8
// 6465.057 us; speedup vs baseline: 1.7855x; 1.7855x over previous
//
#include <hip/hip_runtime.h>
#include <math.h>

// Problem constants: B=8, S=16, CIN=128, H=W=64, D=64
// Padded field layout for conv inputs: [b][c][66 rows][72 cols], value(x,y) at [y+1][x+4],
// borders zero. PF = 8*64*66*72 = 2,433,024 floats.

__device__ __forceinline__ float sigf(float x){ return 1.0f/(1.0f + expf(-x)); }

#define FMA4(A, W, V0, V1, V2, V3) { (A).x += (W)*(V0); (A).y += (W)*(V1); (A).z += (W)*(V2); (A).w += (W)*(V3); }

// ---------------------------------------------------------------------------
// reshape clstm_w (256,128,3,3) -> w3[rk][ocg*8 + g*2 + e], rk = ic*9+k,
// where oc_global = g*64 + ocg*2 + e  (g = gate 0..3, ocg 0..31, e 0..1).
// Thread ocg then owns all 4 gates of channels {2*ocg, 2*ocg+1}.
__global__ __launch_bounds__(256) void k_w3(const float* __restrict__ cw, float* __restrict__ w3){
    int idx = blockIdx.x*256 + threadIdx.x;
    if (idx < 294912){
        int col = idx & 255;            // ocg*8 + g*2 + e
        int rk  = idx >> 8;             // ic*9 + k
        int ocg = col >> 3, j = col & 7;
        int g = j >> 1, e = j & 1;
        int oc = g*64 + ocg*2 + e;
        w3[idx] = cw[oc*1152 + rk];
    }
}

// ---------------------------------------------------------------------------
// 1x1 proj conv + BN partial sums. Writes raw t==0 slice into x0 buffer.
__global__ __launch_bounds__(256) void k_proj(const float* __restrict__ x, const float* __restrict__ pw,
                                              float* __restrict__ x0raw, float* __restrict__ psum,
                                              float* __restrict__ psumsq){
    __shared__ __align__(16) float smem[8192];
    const int tile = blockIdx.x;
    const int n    = blockIdx.y;
    const int tid  = threadIdx.x;
    const int pj = tid & 63, dg = tid >> 6;

    for (int r = tid; r < 8192; r += 256){
        int c = r >> 6, d = r & 63;
        smem[r] = pw[d*128 + c];
    }
    __syncthreads();

    const int p0 = tile*256 + pj*4;
    float4 acc[16];
#pragma unroll
    for (int i=0;i<16;i++) acc[i] = make_float4(0.f,0.f,0.f,0.f);

    const float* xb = x + (((size_t)n) << 19) + p0;
    for (int c = 0; c < 128; ++c){
        float4 xv = *(const float4*)(xb + ((size_t)c << 12));
        const float4* wr = (const float4*)(smem + c*64 + dg*16);
#pragma unroll
        for (int q=0;q<4;++q){
            float4 w4 = wr[q];
            FMA4(acc[q*4+0], w4.x, xv.x, xv.y, xv.z, xv.w);
            FMA4(acc[q*4+1], w4.y, xv.x, xv.y, xv.z, xv.w);
            FMA4(acc[q*4+2], w4.z, xv.x, xv.y, xv.z, xv.w);
            FMA4(acc[q*4+3], w4.w, xv.x, xv.y, xv.z, xv.w);
        }
    }

    const int t = n & 15, b = n >> 4;
    if (t == 0){
#pragma unroll
        for (int i=0;i<16;i++){
            int dd = dg*16 + i;
            *(float4*)(x0raw + (((size_t)(b*64 + dd)) << 12) + p0) = acc[i];
        }
    }
    float ls[16], lss[16];
#pragma unroll
    for (int i=0;i<16;i++){
        float4 a = acc[i];
        ls[i]  = a.x + a.y + a.z + a.w;
        lss[i] = a.x*a.x + a.y*a.y + a.z*a.z + a.w*a.w;
    }
    __syncthreads();
#pragma unroll
    for (int i=0;i<16;i++) smem[pj*65 + dg*16 + i] = ls[i];
    __syncthreads();
    if (tid < 64){
        float s = 0.f;
        for (int p=0;p<64;p++) s += smem[p*65 + tid];
        psum[((n*16 + tile) << 6) + tid] = s;
    }
    __syncthreads();
#pragma unroll
    for (int i=0;i<16;i++) smem[pj*65 + dg*16 + i] = lss[i];
    __syncthreads();
    if (tid < 64){
        float s = 0.f;
        for (int p=0;p<64;p++) s += smem[p*65 + tid];
        psumsq[((n*16 + tile) << 6) + tid] = s;
    }
}

// ---------------------------------------------------------------------------
__global__ __launch_bounds__(64) void k_bnfinal(const float* __restrict__ psum, const float* __restrict__ psumsq,
                                                const float* __restrict__ gamma, const float* __restrict__ beta,
                                                float* __restrict__ scale, float* __restrict__ shift,
                                                float* __restrict__ xmean){
    const int d = threadIdx.x;
    double gs = 0.0, gss = 0.0;
    for (int n=0;n<128;n++){
        float s = 0.f, ss = 0.f;
        for (int tl=0;tl<16;tl++){
            s  += psum  [((n*16+tl)<<6) + d];
            ss += psumsq[((n*16+tl)<<6) + d];
        }
        gs += (double)s; gss += (double)ss;
    }
    double mu  = gs  / 524288.0;
    double var = gss / 524288.0 - mu*mu;
    double sc  = (double)gamma[d] / sqrt(var + 1e-5);
    float scf = (float)sc;
    float shf = (float)((double)beta[d] - mu*sc);
    scale[d] = scf; shift[d] = shf;
    for (int n=0;n<128;n++){
        float s = 0.f;
        for (int tl=0;tl<16;tl++) s += psum[((n*16+tl)<<6) + d];
        xmean[(n<<6) + d] = (s * (1.f/4096.f)) * scf + shf;
    }
}

// ---------------------------------------------------------------------------
// Zero a float4-multiple region (yhat_p | hfA_p | hfB_p | cf, contiguous).
__global__ __launch_bounds__(256) void k_zero(float* __restrict__ z){
    size_t i = ((size_t)blockIdx.x*256 + threadIdx.x)*4;
    *(float4*)(z + i) = make_float4(0.f,0.f,0.f,0.f);
}

// ---------------------------------------------------------------------------
// Apply BN to x0 (in place), write yhat_p interior, init states, P=P_init.
__global__ __launch_bounds__(256) void k_init(const float* __restrict__ scale, const float* __restrict__ shift,
                                              float* __restrict__ x0, float* __restrict__ yhat_p,
                                              const float* __restrict__ Pinit, float* __restrict__ Pg,
                                              float* __restrict__ hQ, float* __restrict__ cQ,
                                              float* __restrict__ hR, float* __restrict__ cR){
    size_t idx = (size_t)blockIdx.x*256 + threadIdx.x;   // 2,097,152 total
    int d = (int)((idx >> 12) & 63);
    float v = x0[idx]*scale[d] + shift[d];
    x0[idx] = v;
    int b = (int)(idx >> 18), r = (int)((idx >> 6) & 63), xx = (int)(idx & 63);
    yhat_p[(((size_t)(b*64 + d))*66 + r + 1)*72 + xx + 4] = v;
    if (idx < 512){ hQ[idx]=0.f; cQ[idx]=0.f; hR[idx]=0.f; cR[idx]=0.f; }
    if (idx < 32768) Pg[idx] = Pinit[idx & 4095];
}

// ---------------------------------------------------------------------------
// ConvLSTM step fused with y_tick. grid (64 rows, 8 b) = 512 blocks (2/CU).
// Thread: pxg = tid&7 (8 px), ocg = tid>>3 (8 oc = 4 gates x 2 channels).
// acc = 64 floats, NO register staging (round-7 spill lesson). 32 chunks of
// 4 ic, single LDS buffer, sync 2-barrier loop (round-6 structure).
// In-register gating (w3 interleave). Tail: h row tile + fcf_w in LDS ->
// y_tick + row partial sums (fused k_ytick).
// LDS 10080 floats: main loop {w [0,9216) | in [9216,10080)};
// tail {fw [0,4352) stride 68 | h_s [4352,8704) stride 68 | red [8704,9280)}.
__global__ __launch_bounds__(256) void k_conv(const float* __restrict__ yhat_p, const float* __restrict__ hfin_p,
                                              float* __restrict__ hfout_p, float* __restrict__ cf,
                                              const float* __restrict__ w3, const float* __restrict__ cb,
                                              const float* __restrict__ fcf_w, const float* __restrict__ fcf_b,
                                              float* __restrict__ ytick,
                                              float* __restrict__ hfpart, float* __restrict__ ytpartR){
    __shared__ __align__(16) float smem[10080];
    const int IB = 9216, HS = 4352, REDZ = 8704;
    const int row = blockIdx.x;
    const int b   = blockIdx.y;
    const int tid = threadIdx.x;
    const int pxg = tid & 7;
    const int ocg = tid >> 3;
    const int px0 = pxg*8;

    float4 acc4[16];                  // [(g*2+e2)*2 + h], h = px 0-3 / 4-7
#pragma unroll
    for (int i=0;i<16;i++) acc4[i] = make_float4(0.f,0.f,0.f,0.f);

    for (int icc = 0; icc < 32; ++icc){
        __syncthreads();
        // ---- stage chunk: 2304 w-float4 (4ic x 9k x 256) + 216 in-float4 (4ic x 3r x 18)
        for (int s = tid; s < 2520; s += 256){
            if (s < 2304){
                *(float4*)(smem + s*4) = ((const float4*)w3)[(size_t)icc*2304 + s];
            } else {
                int si = s - 2304;
                int icl = si/54, rem = si - icl*54, r = rem/18, x4 = rem - r*18;
                int ic  = icc*4 + icl;
                const float* f = (ic < 64) ? yhat_p : hfin_p;
                *(float4*)(smem + IB + si*4) =
                    *(const float4*)(f + (((size_t)(b*64 + (ic & 63)))*66 + row + r)*72 + x4*4);
            }
        }
        __syncthreads();
        // ---- compute ----
#pragma unroll
        for (int icl=0; icl<4; ++icl){
            float v[3][10];
#pragma unroll
            for (int ky=0;ky<3;++ky){
                const float* vp = smem + IB + icl*216 + ky*72 + px0;
                v[ky][0] = vp[3];
                float4 va = *(const float4*)(vp+4);
                float4 vb = *(const float4*)(vp+8);
                v[ky][1]=va.x; v[ky][2]=va.y; v[ky][3]=va.z; v[ky][4]=va.w;
                v[ky][5]=vb.x; v[ky][6]=vb.y; v[ky][7]=vb.z; v[ky][8]=vb.w;
                v[ky][9] = vp[12];
            }
#pragma unroll
            for (int k=0;k<9;++k){
                const int ky = k/3, kx = k - ky*3;
                const float* wr = smem + (icl*9+k)*256 + ocg*8;
                float4 wa  = *(const float4*)(wr);
                float4 wb4 = *(const float4*)(wr+4);
                const float u0=v[ky][kx+0], u1=v[ky][kx+1], u2=v[ky][kx+2], u3=v[ky][kx+3];
                const float u4=v[ky][kx+4], u5=v[ky][kx+5], u6=v[ky][kx+6], u7=v[ky][kx+7];
                FMA4(acc4[0],  wa.x,  u0,u1,u2,u3);  FMA4(acc4[1],  wa.x,  u4,u5,u6,u7);
                FMA4(acc4[2],  wa.y,  u0,u1,u2,u3);  FMA4(acc4[3],  wa.y,  u4,u5,u6,u7);
                FMA4(acc4[4],  wa.z,  u0,u1,u2,u3);  FMA4(acc4[5],  wa.z,  u4,u5,u6,u7);
                FMA4(acc4[6],  wa.w,  u0,u1,u2,u3);  FMA4(acc4[7],  wa.w,  u4,u5,u6,u7);
                FMA4(acc4[8],  wb4.x, u0,u1,u2,u3);  FMA4(acc4[9],  wb4.x, u4,u5,u6,u7);
                FMA4(acc4[10], wb4.y, u0,u1,u2,u3);  FMA4(acc4[11], wb4.y, u4,u5,u6,u7);
                FMA4(acc4[12], wb4.z, u0,u1,u2,u3);  FMA4(acc4[13], wb4.z, u4,u5,u6,u7);
                FMA4(acc4[14], wb4.w, u0,u1,u2,u3);  FMA4(acc4[15], wb4.w, u4,u5,u6,u7);
            }
        }
    }
    __syncthreads();   // all chunk reads done; LDS re-purposed below

    // ---- stage fcf_w into fw region [0,4352), stride 68 (bank-spread) ----
#pragma unroll
    for (int j=0;j<4;++j){
        int s = tid + j*256;               // float4 idx into fcf_w (1024 total)
        int dp = s >> 4, c4 = s & 15;
        *(float4*)(smem + dp*68 + c4*4) = ((const float4*)fcf_w)[s];
    }

    // ---- gating fully in registers: j = g*2+e2, gate order i,f,o,g ----
#pragma unroll
    for (int e2=0;e2<2;++e2){
        const int d = ocg*2 + e2;
        const float biv = cb[d], bfv = cb[64+d], bov = cb[128+d], bgv = cb[192+d];
        const size_t gidx = (((size_t)(b*64 + d)) << 12) + row*64 + px0;
        const size_t pidx = (((size_t)(b*64 + d))*66 + row + 1)*72 + px0 + 4;
#pragma unroll
        for (int h2=0;h2<2;++h2){
            float4 zi = acc4[(0+e2)*2 + h2];
            float4 zf = acc4[(2+e2)*2 + h2];
            float4 zo = acc4[(4+e2)*2 + h2];
            float4 zg = acc4[(6+e2)*2 + h2];
            float4 c_old = *(const float4*)(cf + gidx + h2*4);
            float4 c2, hh;
            c2.x = sigf(zf.x+bfv)*c_old.x + sigf(zi.x+biv)*tanhf(zg.x+bgv); hh.x = sigf(zo.x+bov)*tanhf(c2.x);
            c2.y = sigf(zf.y+bfv)*c_old.y + sigf(zi.y+biv)*tanhf(zg.y+bgv); hh.y = sigf(zo.y+bov)*tanhf(c2.y);
            c2.z = sigf(zf.z+bfv)*c_old.z + sigf(zi.z+biv)*tanhf(zg.z+bgv); hh.z = sigf(zo.z+bov)*tanhf(c2.z);
            c2.w = sigf(zf.w+bfv)*c_old.w + sigf(zi.w+biv)*tanhf(zg.w+bgv); hh.w = sigf(zo.w+bov)*tanhf(c2.w);
            *(float4*)(cf + gidx + h2*4) = c2;
            *(float4*)(hfout_p + pidx + h2*4) = hh;
            *(float4*)(smem + HS + d*68 + px0 + h2*4) = hh;
        }
    }
    __syncthreads();

    // ---- fused y_tick: yt[d'][px] = fcf_b[d'] + sum_d fcf_w[d'][d] * h[d][px] ----
    const int d0 = ocg*2;
    float4 yt[4];
    {
        float b0 = fcf_b[d0], b1 = fcf_b[d0+1];
        yt[0] = make_float4(b0,b0,b0,b0); yt[1] = yt[0];
        yt[2] = make_float4(b1,b1,b1,b1); yt[3] = yt[2];
    }
    for (int d=0; d<64; ++d){
        float4 h0 = *(const float4*)(smem + HS + d*68 + px0);
        float4 h1 = *(const float4*)(smem + HS + d*68 + px0 + 4);
        float w0 = smem[(d0  )*68 + d];
        float w1 = smem[(d0+1)*68 + d];
        FMA4(yt[0], w0, h0.x,h0.y,h0.z,h0.w);
        FMA4(yt[1], w0, h1.x,h1.y,h1.z,h1.w);
        FMA4(yt[2], w1, h0.x,h0.y,h0.z,h0.w);
        FMA4(yt[3], w1, h1.x,h1.y,h1.z,h1.w);
    }
#pragma unroll
    for (int e2=0;e2<2;++e2){
        const int dp = d0 + e2;
        size_t yi = (((size_t)(b*64 + dp)) << 12) + row*64 + px0;
        *(float4*)(ytick + yi)     = yt[e2*2+0];
        *(float4*)(ytick + yi + 4) = yt[e2*2+1];
        float4 a = yt[e2*2], c = yt[e2*2+1];
        smem[REDZ + dp*9 + pxg] = a.x+a.y+a.z+a.w + c.x+c.y+c.z+c.w;
    }
    __syncthreads();
    if (tid < 64){
        float s = 0.f;
#pragma unroll 8
        for (int px=0;px<64;++px) s += smem[HS + tid*68 + px];
        hfpart[((b*64 + row) << 6) + tid] = s;
        float s2 = 0.f;
#pragma unroll
        for (int q=0;q<8;++q) s2 += smem[REDZ + tid*9 + q];
        ytpartR[((b*64 + row) << 6) + tid] = s2;
    }
}

// ---------------------------------------------------------------------------
// Per-step small ops + Kalman update. grid 8 (b), block 256.
__global__ __launch_bounds__(256) void k_small(int t,
        const float* __restrict__ hfpart, const float* __restrict__ ytpartR, const float* __restrict__ xmean,
        const float* __restrict__ fcF_w, const float* __restrict__ fcF_b,
        const float* __restrict__ lq_wih, const float* __restrict__ lq_whh,
        const float* __restrict__ lq_bih, const float* __restrict__ lq_bhh,
        const float* __restrict__ lr_wih, const float* __restrict__ lr_whh,
        const float* __restrict__ lr_bih, const float* __restrict__ lr_bhh,
        const float* __restrict__ fcQ_w, const float* __restrict__ fcQ_b,
        const float* __restrict__ fcR_w, const float* __restrict__ fcR_b,
        float* __restrict__ hQ, float* __restrict__ cQ, float* __restrict__ hR, float* __restrict__ cR,
        float* __restrict__ Pg, float* __restrict__ Kg){
    const int b = blockIdx.x, tid = threadIdx.x;
    __shared__ __align__(16) float aug[64*132];
    __shared__ __align__(16) float Pl[4096];
    __shared__ float hfm[64], ytm[64], xm[64], Fv[64], Qd[64], Rd[64], rds[64];
    __shared__ float hq_s[64], cq_s[64], hr_s[64], cr_s[64];
    __shared__ float gq[256], gr[256];

    if (tid < 64){
        float s = 0.f;
        for (int r=0;r<64;r++) s += hfpart[((b*64 + r) << 6) + tid];
        hfm[tid] = s * (1.f/4096.f);
        float s2 = 0.f;
        for (int r=0;r<64;r++) s2 += ytpartR[((b*64 + r) << 6) + tid];
        ytm[tid] = s2 * (1.f/4096.f);
        xm[tid] = xmean[((b*16 + t) << 6) + tid];
        hq_s[tid] = hQ[b*64+tid]; cq_s[tid] = cQ[b*64+tid];
        hr_s[tid] = hR[b*64+tid]; cr_s[tid] = cR[b*64+tid];
    }
    __syncthreads();
    {
        int j = tid;
        float aq = lq_bih[j] + lq_bhh[j];
        float ar = lr_bih[j] + lr_bhh[j];
        for (int e=0;e<64;e++){
            aq += lq_wih[j*64+e]*ytm[e] + lq_whh[j*64+e]*hq_s[e];
            ar += lr_wih[j*64+e]*xm[e]  + lr_whh[j*64+e]*hr_s[e];
        }
        gq[j] = aq; gr[j] = ar;
    }
    if (tid < 64){
        float a = fcF_b[tid];
        for (int e=0;e<64;e++) a += fcF_w[tid*64+e]*hfm[e];
        Fv[tid] = a;
    }
    __syncthreads();
    if (tid < 64){   // lstm_cell gate order: i, f, g, o
        int dd = tid;
        float gi = gq[dd], gf = gq[64+dd], gg = gq[128+dd], go = gq[192+dd];
        float c2 = sigf(gf)*cq_s[dd] + sigf(gi)*tanhf(gg);
        float h2 = sigf(go)*tanhf(c2);
        cq_s[dd] = c2; hq_s[dd] = h2;
        gi = gr[dd]; gf = gr[64+dd]; gg = gr[128+dd]; go = gr[192+dd];
        c2 = sigf(gf)*cr_s[dd] + sigf(gi)*tanhf(gg);
        h2 = sigf(go)*tanhf(c2);
        cr_s[dd] = c2; hr_s[dd] = h2;
    }
    __syncthreads();
    if (tid < 64){
        float aq_ = fcQ_b[tid], ar_ = fcR_b[tid];
        for (int e=0;e<64;e++){ aq_ += fcQ_w[tid*64+e]*hq_s[e]; ar_ += fcR_w[tid*64+e]*hr_s[e]; }
        Qd[tid] = expf(aq_); Rd[tid] = expf(ar_);
        hQ[b*64+tid] = hq_s[tid]; cQ[b*64+tid] = cq_s[tid];
        hR[b*64+tid] = hr_s[tid]; cR[b*64+tid] = cr_s[tid];
    }
    __syncthreads();
    // P = P*FF + diag(Qd); aug = [A=P+diag(Rd) | P]
    for (int r = tid; r < 4096; r += 256){
        int i = r >> 6, j = r & 63;
        float p = Pg[((size_t)b << 12) + r] * Fv[i]*Fv[j] + (i==j ? Qd[i] : 0.f);
        Pl[r] = p;
        aug[i*132 + 64 + j] = p;
        aug[i*132 + j]      = p + (i==j ? Rd[i] : 0.f);
    }
    __syncthreads();
    const int r_ = tid & 63, cq_ = tid >> 6;
    for (int k = 0; k < 64; ++k){
        float akk = aug[k*132 + k];
        float f = aug[r_*132 + k] / akk;
        if (r_ != k){
#pragma unroll
            for (int u = 0; u < 8; ++u){
                int c4 = cq_*32 + u*4;
                if (c4 + 3 > k){
                    float4 pv = *(const float4*)(aug + k*132 + c4);
                    float4 av = *(const float4*)(aug + r_*132 + c4);
                    av.x = (c4+0 > k) ? av.x - f*pv.x : av.x;
                    av.y = (c4+1 > k) ? av.y - f*pv.y : av.y;
                    av.z = (c4+2 > k) ? av.z - f*pv.z : av.z;
                    av.w = (c4+3 > k) ? av.w - f*pv.w : av.w;
                    *(float4*)(aug + r_*132 + c4) = av;
                }
            }
        }
        __syncthreads();
    }
    if (tid < 64) rds[tid] = 1.0f / aug[tid*132 + tid];
    __syncthreads();
    {
        const int i = tid >> 2, jq = tid & 3;
        float4 tv[4];
#pragma unroll
        for (int q=0;q<4;++q) tv[q] = *(const float4*)(Pl + i*64 + jq*16 + q*4);
        for (int m=0;m<64;++m){
            float kim = aug[m*132 + 64 + i] * rds[m];
#pragma unroll
            for (int q=0;q<4;++q){
                float4 pv = *(const float4*)(Pl + m*64 + jq*16 + q*4);
                tv[q].x -= kim*pv.x; tv[q].y -= kim*pv.y; tv[q].z -= kim*pv.z; tv[q].w -= kim*pv.w;
            }
        }
#pragma unroll
        for (int q=0;q<4;++q) *(float4*)(aug + i*132 + jq*16 + q*4) = tv[q];
    }
    __syncthreads();
    {
        const int i = tid >> 2, jq = tid & 3;
        float4 a2[4];
#pragma unroll
        for (int q=0;q<4;++q) a2[q] = *(const float4*)(aug + i*132 + jq*16 + q*4);
        for (int m=0;m<64;++m){
            float t1im = aug[i*132 + m];
            float kim  = aug[m*132 + 64 + i] * rds[m];
            float coef = rds[m] * (kim * Rd[m] - t1im);
#pragma unroll
            for (int q=0;q<4;++q){
                float4 yv = *(const float4*)(aug + m*132 + 64 + jq*16 + q*4);
                a2[q].x += coef*yv.x; a2[q].y += coef*yv.y; a2[q].z += coef*yv.z; a2[q].w += coef*yv.w;
            }
        }
        size_t base = ((size_t)b << 12) + (size_t)i*64;
#pragma unroll
        for (int q=0;q<4;++q) *(float4*)(Pg + base + jq*16 + q*4) = a2[q];
#pragma unroll
        for (int q=0;q<4;++q){
#pragma unroll
            for (int e=0;e<4;++e){
                int j = jq*16 + q*4 + e;
                Kg[base + j] = aug[j*132 + 64 + i] * rds[j];
            }
        }
    }
}

// ---------------------------------------------------------------------------
// y_hat = y_tick + K(x0 - y_tick); writes PADDED yhat + spatial partial sums.
// grid (32 tiles of 128 px, 8 b), block 256: pj = tid&31 (4 px), dgp = tid>>5 (8 d).
__global__ __launch_bounds__(256) void k_apply(int t, const float* __restrict__ ytick,
                                               const float* __restrict__ x0, const float* __restrict__ Kg,
                                               float* __restrict__ yhat_p, float* __restrict__ featpart){
    __shared__ __align__(16) float kt[4160];   // kt[j*65 + i] = K[i][j]  (conflict-free both ways)
    const int tile = blockIdx.x;
    const int b    = blockIdx.y;
    const int tid  = threadIdx.x;
    const int pj = tid & 31, dgp = tid >> 5;

    for (int r = tid; r < 4096; r += 256){
        int i = r >> 6, j = r & 63;
        kt[j*65 + i] = Kg[((size_t)b << 12) + r];
    }
    __syncthreads();

    const int p0 = tile*128 + pj*4;
    const int rr = p0 >> 6, xx = p0 & 63;
    float4 acc[8];
#pragma unroll
    for (int i=0;i<8;i++) acc[i] = make_float4(0.f,0.f,0.f,0.f);

    for (int j = 0; j < 64; ++j){
        size_t gi = (((size_t)(b*64 + j)) << 12) + p0;
        float4 xv = *(const float4*)(x0 + gi);
        float4 yv = *(const float4*)(ytick + gi);
        float u0 = xv.x - yv.x, u1 = xv.y - yv.y, u2 = xv.z - yv.z, u3 = xv.w - yv.w;
        const float* kr = kt + j*65 + dgp*8;
#pragma unroll
        for (int il=0; il<8; ++il){
            float kv = kr[il];
            FMA4(acc[il], kv, u0,u1,u2,u3);
        }
    }
    float ls[8];
#pragma unroll
    for (int il=0;il<8;++il){
        int d = dgp*8 + il;
        size_t gi = (((size_t)(b*64 + d)) << 12) + p0;
        float4 yv = *(const float4*)(ytick + gi);
        float4 o;
        o.x = yv.x + acc[il].x; o.y = yv.y + acc[il].y; o.z = yv.z + acc[il].z; o.w = yv.w + acc[il].w;
        *(float4*)(yhat_p + (((size_t)(b*64 + d))*66 + rr + 1)*72 + xx + 4) = o;
        ls[il] = o.x + o.y + o.z + o.w;
    }
    __syncthreads();   // kt reads done; reuse as reduction scratch
#pragma unroll
    for (int il=0;il<8;++il) kt[pj*65 + dgp*8 + il] = ls[il];
    __syncthreads();
    if (tid < 64){
        float s = 0.f;
        for (int q=0;q<32;++q) s += kt[q*65 + tid];
        featpart[(((size_t)((t*8 + b)*32 + tile)) << 6) + tid] = s;
    }
}

// ---------------------------------------------------------------------------
__global__ __launch_bounds__(64) void k_head(const float* __restrict__ featpart,
                                             const float* __restrict__ fc_w, const float* __restrict__ fc_b,
                                             const float* __restrict__ fco_w, const float* __restrict__ fco_b,
                                             const float* __restrict__ fca_w, const float* __restrict__ fca_b,
                                             float* __restrict__ out){
    const int bt = blockIdx.x;
    const int b = bt >> 4, t = bt & 15;
    __shared__ float fs[64];
    const int i = threadIdx.x;
    float s = 0.f;
    for (int tile=0;tile<32;tile++) s += featpart[(((size_t)((t*8 + b)*32 + tile)) << 6) + i];
    fs[i] = s * (1.f/4096.f);
    __syncthreads();
    float a = fc_b[i];
    for (int e=0;e<64;e++) a += fc_w[i*64+e]*fs[e];
    a = fmaxf(a, 0.f);
    float po = a * fco_w[i];
    float pa = a * fca_w[i];
    for (int off=32; off; off >>= 1){ po += __shfl_down(po, off); pa += __shfl_down(pa, off); }
    if (i == 0){
        out[bt]       = po + fco_b[0];
        out[128 + bt] = pa + fca_b[0];
    }
}

// ---------------------------------------------------------------------------
extern "C" void kernel_launch(void* const* d_in, const int* in_sizes, int n_in,
                              void* d_out, int out_size, void* d_ws, size_t ws_size,
                              hipStream_t stream){
    const float* x       = (const float*)d_in[0];
    const float* proj_w  = (const float*)d_in[1];
    const float* bn_g    = (const float*)d_in[2];
    const float* bn_b    = (const float*)d_in[3];
    const float* clstm_w = (const float*)d_in[4];
    const float* clstm_b = (const float*)d_in[5];
    const float* lq_wih  = (const float*)d_in[6];
    const float* lq_whh  = (const float*)d_in[7];
    const float* lq_bih  = (const float*)d_in[8];
    const float* lq_bhh  = (const float*)d_in[9];
    const float* lr_wih  = (const float*)d_in[10];
    const float* lr_whh  = (const float*)d_in[11];
    const float* lr_bih  = (const float*)d_in[12];
    const float* lr_bhh  = (const float*)d_in[13];
    const float* fcf_w   = (const float*)d_in[14];
    const float* fcf_b   = (const float*)d_in[15];
    const float* fcF_w   = (const float*)d_in[16];
    const float* fcF_b   = (const float*)d_in[17];
    const float* fcQ_w   = (const float*)d_in[18];
    const float* fcQ_b   = (const float*)d_in[19];
    const float* fcR_w   = (const float*)d_in[20];
    const float* fcR_b   = (const float*)d_in[21];
    const float* P_init  = (const float*)d_in[22];
    const float* fc_w    = (const float*)d_in[23];
    const float* fc_b    = (const float*)d_in[24];
    const float* fco_w   = (const float*)d_in[25];
    const float* fco_b   = (const float*)d_in[26];
    const float* fca_w   = (const float*)d_in[27];
    const float* fca_b   = (const float*)d_in[28];
    float* out = (float*)d_out;
    float* ws  = (float*)d_ws;

    const size_t PF    = 2433024;        // 8*64*66*72 padded field
    const size_t FIELD = 2097152;        // 8*64*4096
    float* yhat_p = ws;                  // PF
    float* hfA_p  = ws + PF;             // PF
    float* hfB_p  = ws + 2*PF;           // PF
    float* cf     = ws + 3*PF;           // FIELD  (zero-span = 3*PF + FIELD)
    float* x0     = cf + FIELD;          // FIELD
    float* ytick  = x0 + FIELD;          // FIELD
    float* w3     = ytick + FIELD;       // 294912
    float* psum   = w3 + 294912;         // 131072
    float* psumsq = psum + 131072;       // 131072
    float* scale  = psumsq + 131072;     // 64
    float* shift  = scale + 64;          // 64
    float* xmean  = shift + 64;          // 8192
    float* hfpart = xmean + 8192;        // 32768
    float* ytpartR= hfpart + 32768;      // 32768
    float* featpart = ytpartR + 32768;   // 262144
    float* hQ     = featpart + 262144;   // 512
    float* cQ     = hQ + 512;
    float* hR     = cQ + 512;
    float* cR     = hR + 512;
    float* Pg     = cR + 512;            // 32768
    float* Kg     = Pg + 32768;          // 32768

    hipLaunchKernelGGL(k_w3, dim3(1152), dim3(256), 0, stream, clstm_w, w3);
    hipLaunchKernelGGL(k_proj, dim3(16,128), dim3(256), 0, stream, x, proj_w, x0, psum, psumsq);
    hipLaunchKernelGGL(k_bnfinal, dim3(1), dim3(64), 0, stream, psum, psumsq, bn_g, bn_b, scale, shift, xmean);
    hipLaunchKernelGGL(k_zero, dim3(9176), dim3(256), 0, stream, ws);   // yhat_p|hfA_p|hfB_p|cf
    hipLaunchKernelGGL(k_init, dim3(8192), dim3(256), 0, stream, scale, shift, x0, yhat_p, P_init, Pg, hQ, cQ, hR, cR);

    for (int t = 0; t < 16; ++t){
        float* hf_in  = (t & 1) ? hfB_p : hfA_p;
        float* hf_out = (t & 1) ? hfA_p : hfB_p;
        hipLaunchKernelGGL(k_conv, dim3(64,8), dim3(256), 0, stream,
                           yhat_p, hf_in, hf_out, cf, w3, clstm_b,
                           fcf_w, fcf_b, ytick, hfpart, ytpartR);
        hipLaunchKernelGGL(k_small, dim3(8), dim3(256), 0, stream, t,
                           hfpart, ytpartR, xmean, fcF_w, fcF_b,
                           lq_wih, lq_whh, lq_bih, lq_bhh,
                           lr_wih, lr_whh, lr_bih, lr_bhh,
                           fcQ_w, fcQ_b, fcR_w, fcR_b,
                           hQ, cQ, hR, cR, Pg, Kg);
        hipLaunchKernelGGL(k_apply, dim3(32,8), dim3(256), 0, stream, t,
                           ytick, x0, Kg, yhat_p, featpart);
    }
    hipLaunchKernelGGL(k_head, dim3(128), dim3(64), 0, stream,
                       featpart, fc_w, fc_b, fco_w, fco_b, fca_w, fca_b, out);
}

// Round 9
// 5713.504 us; speedup vs baseline: 2.0204x; 1.1315x over previous
//
#include <hip/hip_runtime.h>
#include <math.h>

// Problem constants: B=8, S=16, CIN=128, H=W=64, D=64
// Padded field layout for conv inputs: [b][c][66 rows][72 cols], value(x,y) at [y+1][x+4],
// borders zero. PF = 8*64*66*72 = 2,433,024 floats.

__device__ __forceinline__ float sigf(float x){ return 1.0f/(1.0f + expf(-x)); }

#define FMA4(A, W, V0, V1, V2, V3) { (A).x += (W)*(V0); (A).y += (W)*(V1); (A).z += (W)*(V2); (A).w += (W)*(V3); }

// ---------------------------------------------------------------------------
// reshape clstm_w (256,128,3,3) -> w4[rk*256 + w*32 + g*8 + c], rk = ic*9+k,
// oc_global = g*64 + w*8 + c  (wave w owns channels w*8..w*8+7, all 4 gates).
// Also fwT[ch*64 + d'] = fcf_w[d'*64 + ch] for the fused y_tick tail.
__global__ __launch_bounds__(256) void k_w4(const float* __restrict__ cw, const float* __restrict__ fcf_w,
                                            float* __restrict__ w4, float* __restrict__ fwT){
    int idx = blockIdx.x*256 + threadIdx.x;
    if (idx < 294912){
        int col = idx & 255;            // w*32 + g*8 + c
        int rk  = idx >> 8;             // ic*9 + k
        int w = col >> 5, g = (col >> 3) & 3, c = col & 7;
        int oc = g*64 + w*8 + c;
        w4[idx] = cw[oc*1152 + rk];
    } else if (idx < 294912 + 4096){
        int i = idx - 294912;
        int ch = i >> 6, dp = i & 63;
        fwT[i] = fcf_w[dp*64 + ch];
    }
}

// ---------------------------------------------------------------------------
// 1x1 proj conv + BN partial sums. Writes raw t==0 slice into x0 buffer.
__global__ __launch_bounds__(256) void k_proj(const float* __restrict__ x, const float* __restrict__ pw,
                                              float* __restrict__ x0raw, float* __restrict__ psum,
                                              float* __restrict__ psumsq){
    __shared__ __align__(16) float smem[8192];
    const int tile = blockIdx.x;
    const int n    = blockIdx.y;
    const int tid  = threadIdx.x;
    const int pj = tid & 63, dg = tid >> 6;

    for (int r = tid; r < 8192; r += 256){
        int c = r >> 6, d = r & 63;
        smem[r] = pw[d*128 + c];
    }
    __syncthreads();

    const int p0 = tile*256 + pj*4;
    float4 acc[16];
#pragma unroll
    for (int i=0;i<16;i++) acc[i] = make_float4(0.f,0.f,0.f,0.f);

    const float* xb = x + (((size_t)n) << 19) + p0;
    for (int c = 0; c < 128; ++c){
        float4 xv = *(const float4*)(xb + ((size_t)c << 12));
        const float4* wr = (const float4*)(smem + c*64 + dg*16);
#pragma unroll
        for (int q=0;q<4;++q){
            float4 w4 = wr[q];
            FMA4(acc[q*4+0], w4.x, xv.x, xv.y, xv.z, xv.w);
            FMA4(acc[q*4+1], w4.y, xv.x, xv.y, xv.z, xv.w);
            FMA4(acc[q*4+2], w4.z, xv.x, xv.y, xv.z, xv.w);
            FMA4(acc[q*4+3], w4.w, xv.x, xv.y, xv.z, xv.w);
        }
    }

    const int t = n & 15, b = n >> 4;
    if (t == 0){
#pragma unroll
        for (int i=0;i<16;i++){
            int dd = dg*16 + i;
            *(float4*)(x0raw + (((size_t)(b*64 + dd)) << 12) + p0) = acc[i];
        }
    }
    float ls[16], lss[16];
#pragma unroll
    for (int i=0;i<16;i++){
        float4 a = acc[i];
        ls[i]  = a.x + a.y + a.z + a.w;
        lss[i] = a.x*a.x + a.y*a.y + a.z*a.z + a.w*a.w;
    }
    __syncthreads();
#pragma unroll
    for (int i=0;i<16;i++) smem[pj*65 + dg*16 + i] = ls[i];
    __syncthreads();
    if (tid < 64){
        float s = 0.f;
        for (int p=0;p<64;p++) s += smem[p*65 + tid];
        psum[((n*16 + tile) << 6) + tid] = s;
    }
    __syncthreads();
#pragma unroll
    for (int i=0;i<16;i++) smem[pj*65 + dg*16 + i] = lss[i];
    __syncthreads();
    if (tid < 64){
        float s = 0.f;
        for (int p=0;p<64;p++) s += smem[p*65 + tid];
        psumsq[((n*16 + tile) << 6) + tid] = s;
    }
}

// ---------------------------------------------------------------------------
__global__ __launch_bounds__(64) void k_bnfinal(const float* __restrict__ psum, const float* __restrict__ psumsq,
                                                const float* __restrict__ gamma, const float* __restrict__ beta,
                                                float* __restrict__ scale, float* __restrict__ shift,
                                                float* __restrict__ xmean){
    const int d = threadIdx.x;
    double gs = 0.0, gss = 0.0;
    for (int n=0;n<128;n++){
        float s = 0.f, ss = 0.f;
        for (int tl=0;tl<16;tl++){
            s  += psum  [((n*16+tl)<<6) + d];
            ss += psumsq[((n*16+tl)<<6) + d];
        }
        gs += (double)s; gss += (double)ss;
    }
    double mu  = gs  / 524288.0;
    double var = gss / 524288.0 - mu*mu;
    double sc  = (double)gamma[d] / sqrt(var + 1e-5);
    float scf = (float)sc;
    float shf = (float)((double)beta[d] - mu*sc);
    scale[d] = scf; shift[d] = shf;
    for (int n=0;n<128;n++){
        float s = 0.f;
        for (int tl=0;tl<16;tl++) s += psum[((n*16+tl)<<6) + d];
        xmean[(n<<6) + d] = (s * (1.f/4096.f)) * scf + shf;
    }
}

// ---------------------------------------------------------------------------
// Zero a float4-multiple region (yhat_p | hfA_p | hfB_p | cf, contiguous).
__global__ __launch_bounds__(256) void k_zero(float* __restrict__ z){
    size_t i = ((size_t)blockIdx.x*256 + threadIdx.x)*4;
    *(float4*)(z + i) = make_float4(0.f,0.f,0.f,0.f);
}

// ---------------------------------------------------------------------------
// Apply BN to x0 (in place), write yhat_p interior, init states, P=P_init.
__global__ __launch_bounds__(256) void k_init(const float* __restrict__ scale, const float* __restrict__ shift,
                                              float* __restrict__ x0, float* __restrict__ yhat_p,
                                              const float* __restrict__ Pinit, float* __restrict__ Pg,
                                              float* __restrict__ hQ, float* __restrict__ cQ,
                                              float* __restrict__ hR, float* __restrict__ cR){
    size_t idx = (size_t)blockIdx.x*256 + threadIdx.x;   // 2,097,152 total
    int d = (int)((idx >> 12) & 63);
    float v = x0[idx]*scale[d] + shift[d];
    x0[idx] = v;
    int b = (int)(idx >> 18), r = (int)((idx >> 6) & 63), xx = (int)(idx & 63);
    yhat_p[(((size_t)(b*64 + d))*66 + r + 1)*72 + xx + 4] = v;
    if (idx < 512){ hQ[idx]=0.f; cQ[idx]=0.f; hR[idx]=0.f; cR[idx]=0.f; }
    if (idx < 32768) Pg[idx] = Pinit[idx & 4095];
}

// ---------------------------------------------------------------------------
// ConvLSTM step fused with y_tick. grid (64 rows, 8 b) = 512 blocks of 512 thr
// (2 blocks/CU = 16 waves/CU = 4 waves/SIMD).
// Wave-uniform channel ownership: lane = px (0..63), wave w owns channels
// w*8..w*8+7 (all 4 gates). Weights are wave-uniform -> scalar s_load path
// (v_fmac with SGPR src), ZERO weight traffic through LDS/VGPR loads.
// LDS stages only inputs: 4ic x 3 rows x 72 = 864 floats/chunk.
// acc[4][8] = 32 floats. Gating fully in-register. Fused y_tick tail via
// h_lds/yt_lds exchange + fwT uniform scalar loads.
// LDS: in_stage [0,864) | h_lds [864,5024) stride 65 | yt_lds [5024,9184).
__global__ __launch_bounds__(512) void k_conv(const float* __restrict__ yhat_p, const float* __restrict__ hfin_p,
                                              float* __restrict__ hfout_p, float* __restrict__ cf,
                                              const float* __restrict__ w4, const float* __restrict__ cb,
                                              const float* __restrict__ fwT, const float* __restrict__ fcf_b,
                                              float* __restrict__ ytick,
                                              float* __restrict__ hfpart, float* __restrict__ ytpartR){
    __shared__ __align__(16) float smem[9184];
    const int HL = 864, YL = 5024;
    const int row = blockIdx.x;
    const int b   = blockIdx.y;
    const int tid = threadIdx.x;
    const int px  = tid & 63;
    const int w   = __builtin_amdgcn_readfirstlane(tid >> 6);   // wave-uniform

    float acc[4][8];
#pragma unroll
    for (int g=0;g<4;++g)
#pragma unroll
        for (int c=0;c<8;++c) acc[g][c] = 0.f;

    // staging indices (tid < 216): slot tid covers floats [tid*4, tid*4+4) of
    // the [icl][3 rows][72] chunk image.
    int s_icl=0, s_r=0, s_x4=0;
    if (tid < 216){
        s_icl = tid/54; int rem = tid - s_icl*54; s_r = rem/18; s_x4 = rem - s_r*18;
    }

    for (int icc = 0; icc < 32; ++icc){
        __syncthreads();
        if (tid < 216){
            int ic = icc*4 + s_icl;
            const float* f = (ic < 64) ? yhat_p : hfin_p;
            *(float4*)(smem + tid*4) =
                *(const float4*)(f + (((size_t)(b*64 + (ic & 63)))*66 + row + s_r)*72 + s_x4*4);
        }
        __syncthreads();
#pragma unroll 1
        for (int icl = 0; icl < 4; ++icl){
            const float* ib = smem + icl*216 + px + 3;
            const float v0 = ib[0],   v1 = ib[1],   v2 = ib[2];
            const float v3 = ib[72],  v4 = ib[73],  v5 = ib[74];
            const float v6 = ib[144], v7 = ib[145], v8 = ib[146];
            const float* wp = w4 + ((size_t)(icc*36 + icl*9) << 8) + w*32;  // uniform
#define WG(KI, VAL) { const float* q_ = wp + (KI)*256; \
    _Pragma("unroll") for (int g=0;g<4;++g) \
    _Pragma("unroll") for (int c=0;c<8;++c) acc[g][c] += q_[g*8+c]*(VAL); }
            WG(0,v0) WG(1,v1) WG(2,v2)
            WG(3,v3) WG(4,v4) WG(5,v5)
            WG(6,v6) WG(7,v7) WG(8,v8)
#undef WG
        }
    }

    // ---- gating fully in registers (gate order i,f,o,g) ----
#pragma unroll
    for (int c=0;c<8;++c){
        const int d = w*8 + c;
        const float biv = cb[d], bfv = cb[64+d], bov = cb[128+d], bgv = cb[192+d];
        const size_t gidx = (((size_t)(b*64 + d)) << 12) + row*64 + px;
        float c_old = cf[gidx];
        float c2 = sigf(acc[1][c]+bfv)*c_old + sigf(acc[0][c]+biv)*tanhf(acc[3][c]+bgv);
        float hh = sigf(acc[2][c]+bov)*tanhf(c2);
        cf[gidx] = c2;
        hfout_p[(((size_t)(b*64 + d))*66 + row + 1)*72 + px + 4] = hh;
        smem[HL + d*65 + px] = hh;
    }
    __syncthreads();

    // ---- fused y_tick: wave w computes d' = w*8..w*8+7 for its lane's px ----
    float yt[8];
#pragma unroll
    for (int j=0;j<8;++j) yt[j] = fcf_b[w*8 + j];
    for (int ch = 0; ch < 64; ++ch){
        float hv = smem[HL + ch*65 + px];
        const float* fp = fwT + ch*64 + w*8;    // uniform
#pragma unroll
        for (int j=0;j<8;++j) yt[j] += fp[j]*hv;
    }
#pragma unroll
    for (int j=0;j<8;++j){
        const int dp = w*8 + j;
        ytick[(((size_t)(b*64 + dp)) << 12) + row*64 + px] = yt[j];
        smem[YL + dp*65 + px] = yt[j];
    }
    __syncthreads();
    if (tid < 64){
        float s = 0.f, s2 = 0.f;
#pragma unroll 8
        for (int pxx=0; pxx<64; ++pxx){
            s  += smem[HL + tid*65 + pxx];
            s2 += smem[YL + tid*65 + pxx];
        }
        hfpart [((b*64 + row) << 6) + tid] = s;
        ytpartR[((b*64 + row) << 6) + tid] = s2;
    }
}

// ---------------------------------------------------------------------------
// Per-step small ops + Kalman update. grid 8 (b), block 256.
__global__ __launch_bounds__(256) void k_small(int t,
        const float* __restrict__ hfpart, const float* __restrict__ ytpartR, const float* __restrict__ xmean,
        const float* __restrict__ fcF_w, const float* __restrict__ fcF_b,
        const float* __restrict__ lq_wih, const float* __restrict__ lq_whh,
        const float* __restrict__ lq_bih, const float* __restrict__ lq_bhh,
        const float* __restrict__ lr_wih, const float* __restrict__ lr_whh,
        const float* __restrict__ lr_bih, const float* __restrict__ lr_bhh,
        const float* __restrict__ fcQ_w, const float* __restrict__ fcQ_b,
        const float* __restrict__ fcR_w, const float* __restrict__ fcR_b,
        float* __restrict__ hQ, float* __restrict__ cQ, float* __restrict__ hR, float* __restrict__ cR,
        float* __restrict__ Pg, float* __restrict__ Kg){
    const int b = blockIdx.x, tid = threadIdx.x;
    __shared__ __align__(16) float aug[64*132];
    __shared__ __align__(16) float Pl[4096];
    __shared__ float hfm[64], ytm[64], xm[64], Fv[64], Qd[64], Rd[64], rds[64];
    __shared__ float hq_s[64], cq_s[64], hr_s[64], cr_s[64];
    __shared__ float gq[256], gr[256];

    if (tid < 64){
        float s = 0.f;
        for (int r=0;r<64;r++) s += hfpart[((b*64 + r) << 6) + tid];
        hfm[tid] = s * (1.f/4096.f);
        float s2 = 0.f;
        for (int r=0;r<64;r++) s2 += ytpartR[((b*64 + r) << 6) + tid];
        ytm[tid] = s2 * (1.f/4096.f);
        xm[tid] = xmean[((b*16 + t) << 6) + tid];
        hq_s[tid] = hQ[b*64+tid]; cq_s[tid] = cQ[b*64+tid];
        hr_s[tid] = hR[b*64+tid]; cr_s[tid] = cR[b*64+tid];
    }
    __syncthreads();
    {
        int j = tid;
        float aq = lq_bih[j] + lq_bhh[j];
        float ar = lr_bih[j] + lr_bhh[j];
        for (int e=0;e<64;e++){
            aq += lq_wih[j*64+e]*ytm[e] + lq_whh[j*64+e]*hq_s[e];
            ar += lr_wih[j*64+e]*xm[e]  + lr_whh[j*64+e]*hr_s[e];
        }
        gq[j] = aq; gr[j] = ar;
    }
    if (tid < 64){
        float a = fcF_b[tid];
        for (int e=0;e<64;e++) a += fcF_w[tid*64+e]*hfm[e];
        Fv[tid] = a;
    }
    __syncthreads();
    if (tid < 64){   // lstm_cell gate order: i, f, g, o
        int dd = tid;
        float gi = gq[dd], gf = gq[64+dd], gg = gq[128+dd], go = gq[192+dd];
        float c2 = sigf(gf)*cq_s[dd] + sigf(gi)*tanhf(gg);
        float h2 = sigf(go)*tanhf(c2);
        cq_s[dd] = c2; hq_s[dd] = h2;
        gi = gr[dd]; gf = gr[64+dd]; gg = gr[128+dd]; go = gr[192+dd];
        c2 = sigf(gf)*cr_s[dd] + sigf(gi)*tanhf(gg);
        h2 = sigf(go)*tanhf(c2);
        cr_s[dd] = c2; hr_s[dd] = h2;
    }
    __syncthreads();
    if (tid < 64){
        float aq_ = fcQ_b[tid], ar_ = fcR_b[tid];
        for (int e=0;e<64;e++){ aq_ += fcQ_w[tid*64+e]*hq_s[e]; ar_ += fcR_w[tid*64+e]*hr_s[e]; }
        Qd[tid] = expf(aq_); Rd[tid] = expf(ar_);
        hQ[b*64+tid] = hq_s[tid]; cQ[b*64+tid] = cq_s[tid];
        hR[b*64+tid] = hr_s[tid]; cR[b*64+tid] = cr_s[tid];
    }
    __syncthreads();
    // P = P*FF + diag(Qd); aug = [A=P+diag(Rd) | P]
    for (int r = tid; r < 4096; r += 256){
        int i = r >> 6, j = r & 63;
        float p = Pg[((size_t)b << 12) + r] * Fv[i]*Fv[j] + (i==j ? Qd[i] : 0.f);
        Pl[r] = p;
        aug[i*132 + 64 + j] = p;
        aug[i*132 + j]      = p + (i==j ? Rd[i] : 0.f);
    }
    __syncthreads();
    const int r_ = tid & 63, cq_ = tid >> 6;
    for (int k = 0; k < 64; ++k){
        float akk = aug[k*132 + k];
        float f = aug[r_*132 + k] / akk;
        if (r_ != k){
#pragma unroll
            for (int u = 0; u < 8; ++u){
                int c4 = cq_*32 + u*4;
                if (c4 + 3 > k){
                    float4 pv = *(const float4*)(aug + k*132 + c4);
                    float4 av = *(const float4*)(aug + r_*132 + c4);
                    av.x = (c4+0 > k) ? av.x - f*pv.x : av.x;
                    av.y = (c4+1 > k) ? av.y - f*pv.y : av.y;
                    av.z = (c4+2 > k) ? av.z - f*pv.z : av.z;
                    av.w = (c4+3 > k) ? av.w - f*pv.w : av.w;
                    *(float4*)(aug + r_*132 + c4) = av;
                }
            }
        }
        __syncthreads();
    }
    if (tid < 64) rds[tid] = 1.0f / aug[tid*132 + tid];
    __syncthreads();
    {
        const int i = tid >> 2, jq = tid & 3;
        float4 tv[4];
#pragma unroll
        for (int q=0;q<4;++q) tv[q] = *(const float4*)(Pl + i*64 + jq*16 + q*4);
        for (int m=0;m<64;++m){
            float kim = aug[m*132 + 64 + i] * rds[m];
#pragma unroll
            for (int q=0;q<4;++q){
                float4 pv = *(const float4*)(Pl + m*64 + jq*16 + q*4);
                tv[q].x -= kim*pv.x; tv[q].y -= kim*pv.y; tv[q].z -= kim*pv.z; tv[q].w -= kim*pv.w;
            }
        }
#pragma unroll
        for (int q=0;q<4;++q) *(float4*)(aug + i*132 + jq*16 + q*4) = tv[q];
    }
    __syncthreads();
    {
        const int i = tid >> 2, jq = tid & 3;
        float4 a2[4];
#pragma unroll
        for (int q=0;q<4;++q) a2[q] = *(const float4*)(aug + i*132 + jq*16 + q*4);
        for (int m=0;m<64;++m){
            float t1im = aug[i*132 + m];
            float kim  = aug[m*132 + 64 + i] * rds[m];
            float coef = rds[m] * (kim * Rd[m] - t1im);
#pragma unroll
            for (int q=0;q<4;++q){
                float4 yv = *(const float4*)(aug + m*132 + 64 + jq*16 + q*4);
                a2[q].x += coef*yv.x; a2[q].y += coef*yv.y; a2[q].z += coef*yv.z; a2[q].w += coef*yv.w;
            }
        }
        size_t base = ((size_t)b << 12) + (size_t)i*64;
#pragma unroll
        for (int q=0;q<4;++q) *(float4*)(Pg + base + jq*16 + q*4) = a2[q];
#pragma unroll
        for (int q=0;q<4;++q){
#pragma unroll
            for (int e=0;e<4;++e){
                int j = jq*16 + q*4 + e;
                Kg[base + j] = aug[j*132 + 64 + i] * rds[j];
            }
        }
    }
}

// ---------------------------------------------------------------------------
// y_hat = y_tick + K(x0 - y_tick); writes PADDED yhat + spatial partial sums.
// grid (32 tiles of 128 px, 8 b), block 256: pj = tid&31 (4 px), dgp = tid>>5 (8 d).
__global__ __launch_bounds__(256) void k_apply(int t, const float* __restrict__ ytick,
                                               const float* __restrict__ x0, const float* __restrict__ Kg,
                                               float* __restrict__ yhat_p, float* __restrict__ featpart){
    __shared__ __align__(16) float kt[4160];   // kt[j*65 + i] = K[i][j]  (conflict-free both ways)
    const int tile = blockIdx.x;
    const int b    = blockIdx.y;
    const int tid  = threadIdx.x;
    const int pj = tid & 31, dgp = tid >> 5;

    for (int r = tid; r < 4096; r += 256){
        int i = r >> 6, j = r & 63;
        kt[j*65 + i] = Kg[((size_t)b << 12) + r];
    }
    __syncthreads();

    const int p0 = tile*128 + pj*4;
    const int rr = p0 >> 6, xx = p0 & 63;
    float4 acc[8];
#pragma unroll
    for (int i=0;i<8;i++) acc[i] = make_float4(0.f,0.f,0.f,0.f);

    for (int j = 0; j < 64; ++j){
        size_t gi = (((size_t)(b*64 + j)) << 12) + p0;
        float4 xv = *(const float4*)(x0 + gi);
        float4 yv = *(const float4*)(ytick + gi);
        float u0 = xv.x - yv.x, u1 = xv.y - yv.y, u2 = xv.z - yv.z, u3 = xv.w - yv.w;
        const float* kr = kt + j*65 + dgp*8;
#pragma unroll
        for (int il=0; il<8; ++il){
            float kv = kr[il];
            FMA4(acc[il], kv, u0,u1,u2,u3);
        }
    }
    float ls[8];
#pragma unroll
    for (int il=0;il<8;++il){
        int d = dgp*8 + il;
        size_t gi = (((size_t)(b*64 + d)) << 12) + p0;
        float4 yv = *(const float4*)(ytick + gi);
        float4 o;
        o.x = yv.x + acc[il].x; o.y = yv.y + acc[il].y; o.z = yv.z + acc[il].z; o.w = yv.w + acc[il].w;
        *(float4*)(yhat_p + (((size_t)(b*64 + d))*66 + rr + 1)*72 + xx + 4) = o;
        ls[il] = o.x + o.y + o.z + o.w;
    }
    __syncthreads();   // kt reads done; reuse as reduction scratch
#pragma unroll
    for (int il=0;il<8;++il) kt[pj*65 + dgp*8 + il] = ls[il];
    __syncthreads();
    if (tid < 64){
        float s = 0.f;
        for (int q=0;q<32;++q) s += kt[q*65 + tid];
        featpart[(((size_t)((t*8 + b)*32 + tile)) << 6) + tid] = s;
    }
}

// ---------------------------------------------------------------------------
__global__ __launch_bounds__(64) void k_head(const float* __restrict__ featpart,
                                             const float* __restrict__ fc_w, const float* __restrict__ fc_b,
                                             const float* __restrict__ fco_w, const float* __restrict__ fco_b,
                                             const float* __restrict__ fca_w, const float* __restrict__ fca_b,
                                             float* __restrict__ out){
    const int bt = blockIdx.x;
    const int b = bt >> 4, t = bt & 15;
    __shared__ float fs[64];
    const int i = threadIdx.x;
    float s = 0.f;
    for (int tile=0;tile<32;tile++) s += featpart[(((size_t)((t*8 + b)*32 + tile)) << 6) + i];
    fs[i] = s * (1.f/4096.f);
    __syncthreads();
    float a = fc_b[i];
    for (int e=0;e<64;e++) a += fc_w[i*64+e]*fs[e];
    a = fmaxf(a, 0.f);
    float po = a * fco_w[i];
    float pa = a * fca_w[i];
    for (int off=32; off; off >>= 1){ po += __shfl_down(po, off); pa += __shfl_down(pa, off); }
    if (i == 0){
        out[bt]       = po + fco_b[0];
        out[128 + bt] = pa + fca_b[0];
    }
}

// ---------------------------------------------------------------------------
extern "C" void kernel_launch(void* const* d_in, const int* in_sizes, int n_in,
                              void* d_out, int out_size, void* d_ws, size_t ws_size,
                              hipStream_t stream){
    const float* x       = (const float*)d_in[0];
    const float* proj_w  = (const float*)d_in[1];
    const float* bn_g    = (const float*)d_in[2];
    const float* bn_b    = (const float*)d_in[3];
    const float* clstm_w = (const float*)d_in[4];
    const float* clstm_b = (const float*)d_in[5];
    const float* lq_wih  = (const float*)d_in[6];
    const float* lq_whh  = (const float*)d_in[7];
    const float* lq_bih  = (const float*)d_in[8];
    const float* lq_bhh  = (const float*)d_in[9];
    const float* lr_wih  = (const float*)d_in[10];
    const float* lr_whh  = (const float*)d_in[11];
    const float* lr_bih  = (const float*)d_in[12];
    const float* lr_bhh  = (const float*)d_in[13];
    const float* fcf_w   = (const float*)d_in[14];
    const float* fcf_b   = (const float*)d_in[15];
    const float* fcF_w   = (const float*)d_in[16];
    const float* fcF_b   = (const float*)d_in[17];
    const float* fcQ_w   = (const float*)d_in[18];
    const float* fcQ_b   = (const float*)d_in[19];
    const float* fcR_w   = (const float*)d_in[20];
    const float* fcR_b   = (const float*)d_in[21];
    const float* P_init  = (const float*)d_in[22];
    const float* fc_w    = (const float*)d_in[23];
    const float* fc_b    = (const float*)d_in[24];
    const float* fco_w   = (const float*)d_in[25];
    const float* fco_b   = (const float*)d_in[26];
    const float* fca_w   = (const float*)d_in[27];
    const float* fca_b   = (const float*)d_in[28];
    float* out = (float*)d_out;
    float* ws  = (float*)d_ws;

    const size_t PF    = 2433024;        // 8*64*66*72 padded field
    const size_t FIELD = 2097152;        // 8*64*4096
    float* yhat_p = ws;                  // PF
    float* hfA_p  = ws + PF;             // PF
    float* hfB_p  = ws + 2*PF;           // PF
    float* cf     = ws + 3*PF;           // FIELD  (zero-span = 3*PF + FIELD)
    float* x0     = cf + FIELD;          // FIELD
    float* ytick  = x0 + FIELD;          // FIELD
    float* w4     = ytick + FIELD;       // 294912
    float* fwT    = w4 + 294912;         // 4096
    float* psum   = fwT + 4096;          // 131072
    float* psumsq = psum + 131072;       // 131072
    float* scale  = psumsq + 131072;     // 64
    float* shift  = scale + 64;          // 64
    float* xmean  = shift + 64;          // 8192
    float* hfpart = xmean + 8192;        // 32768
    float* ytpartR= hfpart + 32768;      // 32768
    float* featpart = ytpartR + 32768;   // 262144
    float* hQ     = featpart + 262144;   // 512
    float* cQ     = hQ + 512;
    float* hR     = cQ + 512;
    float* cR     = hR + 512;
    float* Pg     = cR + 512;            // 32768
    float* Kg     = Pg + 32768;          // 32768

    hipLaunchKernelGGL(k_w4, dim3(1168), dim3(256), 0, stream, clstm_w, fcf_w, w4, fwT);
    hipLaunchKernelGGL(k_proj, dim3(16,128), dim3(256), 0, stream, x, proj_w, x0, psum, psumsq);
    hipLaunchKernelGGL(k_bnfinal, dim3(1), dim3(64), 0, stream, psum, psumsq, bn_g, bn_b, scale, shift, xmean);
    hipLaunchKernelGGL(k_zero, dim3(9176), dim3(256), 0, stream, ws);   // yhat_p|hfA_p|hfB_p|cf
    hipLaunchKernelGGL(k_init, dim3(8192), dim3(256), 0, stream, scale, shift, x0, yhat_p, P_init, Pg, hQ, cQ, hR, cR);

    for (int t = 0; t < 16; ++t){
        float* hf_in  = (t & 1) ? hfB_p : hfA_p;
        float* hf_out = (t & 1) ? hfA_p : hfB_p;
        hipLaunchKernelGGL(k_conv, dim3(64,8), dim3(512), 0, stream,
                           yhat_p, hf_in, hf_out, cf, w4, clstm_b,
                           fwT, fcf_b, ytick, hfpart, ytpartR);
        hipLaunchKernelGGL(k_small, dim3(8), dim3(256), 0, stream, t,
                           hfpart, ytpartR, xmean, fcF_w, fcF_b,
                           lq_wih, lq_whh, lq_bih, lq_bhh,
                           lr_wih, lr_whh, lr_bih, lr_bhh,
                           fcQ_w, fcQ_b, fcR_w, fcR_b,
                           hQ, cQ, hR, cR, Pg, Kg);
        hipLaunchKernelGGL(k_apply, dim3(32,8), dim3(256), 0, stream, t,
                           ytick, x0, Kg, yhat_p, featpart);
    }
    hipLaunchKernelGGL(k_head, dim3(128), dim3(64), 0, stream,
                       featpart, fc_w, fc_b, fco_w, fco_b, fca_w, fca_b, out);
}